// Round 19
// baseline (466.832 us; speedup 1.0000x reference)
//
#include <hip/hip_runtime.h>

#define EPSQ 1e-5f

typedef int i32x4 __attribute__((ext_vector_type(4)));
typedef float f32x4n __attribute__((ext_vector_type(4)));   // native vec for NT loads

// ---------- helpers ----------
__device__ __forceinline__ unsigned short f2bf(float f) {
  unsigned int b = __builtin_bit_cast(unsigned int, f);
  b += 0x7FFFu + ((b >> 16) & 1u);            // RNE
  return (unsigned short)(b >> 16);
}
__device__ __forceinline__ float bf2f(unsigned short u) {
  unsigned int b = ((unsigned int)u) << 16;
  return __builtin_bit_cast(float, b);
}
// weights: ternary clip to [-1,1]
__device__ __forceinline__ int packw4(float a, float b, float c, float d, float inv) {
  int qa = (int)fminf(fmaxf(rintf(a * inv), -1.0f), 1.0f);
  int qb = (int)fminf(fmaxf(rintf(b * inv), -1.0f), 1.0f);
  int qc = (int)fminf(fmaxf(rintf(c * inv), -1.0f), 1.0f);
  int qd = (int)fminf(fmaxf(rintf(d * inv), -1.0f), 1.0f);
  return (qa & 255) | ((qb & 255) << 8) | ((qc & 255) << 16) | ((qd & 255) << 24);
}
// activations: clip to [-128,127]
__device__ __forceinline__ int packa4(float a, float b, float c, float d, float s) {
  int qa = (int)fminf(fmaxf(rintf(a * s), -128.0f), 127.0f);
  int qb = (int)fminf(fmaxf(rintf(b * s), -128.0f), 127.0f);
  int qc = (int)fminf(fmaxf(rintf(c * s), -128.0f), 127.0f);
  int qd = (int)fminf(fmaxf(rintf(d * s), -128.0f), 127.0f);
  return (qa & 255) | ((qb & 255) << 8) | ((qc & 255) << 16) | ((qd & 255) << 24);
}

// ---------- weight tensor table (flattened chunk mapping) ----------
struct WTbl {
  const float* p[6];
  unsigned char* q[6];
  unsigned int cum[7];
};

// ---------- stage 1: per-chunk |w| partial sums; NT reads (proven round 13) ----------
__global__ __launch_bounds__(256) void wmean_partial(WTbl tbl, double* __restrict__ part) {
  const int b = blockIdx.x;
  int t = 0;
#pragma unroll
  for (int i = 1; i < 6; ++i) t += (b >= (int)tbl.cum[i]);
  const f32x4n* __restrict__ p = (const f32x4n*)tbl.p[t];
  const unsigned int base = (unsigned)(b - (int)tbl.cum[t]) * 2048u + threadIdx.x;
  f32x4n v[8];
#pragma unroll
  for (int u = 0; u < 8; ++u) v[u] = __builtin_nontemporal_load(p + base + (unsigned)u * 256u);
  double s = 0.0;
#pragma unroll
  for (int u = 0; u < 8; ++u)
    s += (double)(fabsf(v[u][0]) + fabsf(v[u][1])) + (double)(fabsf(v[u][2]) + fabsf(v[u][3]));
  for (int off = 32; off; off >>= 1) s += __shfl_xor(s, off);
  __shared__ double wsum[4];
  if ((threadIdx.x & 63) == 0) wsum[threadIdx.x >> 6] = s;
  __syncthreads();
  if (threadIdx.x == 0) part[b] = (wsum[0] + wsum[1]) + (wsum[2] + wsum[3]);
}

// ---------- stage 2: finalize means ----------
__global__ __launch_bounds__(256) void wmean_final(const double* __restrict__ part,
                                                   WTbl tbl, float* wmean) {
  for (int t = 0; t < 6; ++t) {
    const int lo = (int)tbl.cum[t], hi = (int)tbl.cum[t + 1];
    double s = 0.0;
    for (int i = lo + (int)threadIdx.x; i < hi; i += 256) s += part[i];
    for (int off = 32; off; off >>= 1) s += __shfl_xor(s, off);
    __shared__ double w4[4];
    if ((threadIdx.x & 63) == 0) w4[threadIdx.x >> 6] = s;
    __syncthreads();
    if (threadIdx.x == 0) {
      const double n = (double)(hi - lo) * 8192.0;
      float m = (float)(((w4[0] + w4[1]) + (w4[2] + w4[3])) / n);
      if (m < EPSQ) m = EPSQ;
      wmean[t] = m;
    }
    __syncthreads();
  }
}

// ---------- stage 3: ternary quantize -> int8; NT reads ----------
__global__ __launch_bounds__(256) void wquant(WTbl tbl, const float* wmean) {
  const int b = blockIdx.x;
  int t = 0;
#pragma unroll
  for (int i = 1; i < 6; ++i) t += (b >= (int)tbl.cum[i]);
  const float inv = 1.0f / wmean[t];
  const f32x4n* __restrict__ p = (const f32x4n*)tbl.p[t];
  int* __restrict__ q = (int*)tbl.q[t];
  const unsigned int base = (unsigned)(b - (int)tbl.cum[t]) * 2048u + threadIdx.x;
  f32x4n v[8];
#pragma unroll
  for (int u = 0; u < 8; ++u) v[u] = __builtin_nontemporal_load(p + base + (unsigned)u * 256u);
#pragma unroll
  for (int u = 0; u < 8; ++u)
    q[base + (unsigned)u * 256u] = packw4(v[u][0], v[u][1], v[u][2], v[u][3], inv);
}

// ---------- block max reduce helper ----------
__device__ __forceinline__ float block_max256(float m) {
  for (int off = 32; off; off >>= 1) m = fmaxf(m, __shfl_xor(m, off));
  __shared__ float wm[4];
  if ((threadIdx.x & 63) == 0) wm[threadIdx.x >> 6] = m;
  __syncthreads();
  return fmaxf(fmaxf(wm[0], wm[1]), fmaxf(wm[2], wm[3]));
}

// ---------- act quant: concat(x,y,z) row (6144) -> int8 + rsx ----------
__global__ __launch_bounds__(256) void aq_cat(const float* x, const float* y, const float* z,
                                              unsigned char* q, float* rsx) {
  const int row = blockIdx.x, tid = threadIdx.x;
  const float4* px = (const float4*)(x + (size_t)row * 2048);
  const float4* py = (const float4*)(y + (size_t)row * 2048);
  const float4* pz = (const float4*)(z + (size_t)row * 2048);
  float4 v[6];
  v[0] = px[tid]; v[1] = px[tid + 256];
  v[2] = py[tid]; v[3] = py[tid + 256];
  v[4] = pz[tid]; v[5] = pz[tid + 256];
  float m = 0.0f;
#pragma unroll
  for (int k = 0; k < 6; ++k)
    m = fmaxf(m, fmaxf(fmaxf(fabsf(v[k].x), fabsf(v[k].y)), fmaxf(fabsf(v[k].z), fabsf(v[k].w))));
  m = fmaxf(block_max256(m), EPSQ);
  const float s = 127.0f / m;
  if (tid == 0) rsx[row] = m / 127.0f;
  int* qr = (int*)(q + (size_t)row * 6144);
#pragma unroll
  for (int k = 0; k < 6; ++k) qr[k * 256 + tid] = packa4(v[k].x, v[k].y, v[k].z, v[k].w, s);
}

// ---------- act quant: bf16 row (8192) -> int8 ----------
__global__ __launch_bounds__(256) void aq_bf16(const unsigned short* u, unsigned char* q, float* rsx) {
  const int row = blockIdx.x, tid = threadIdx.x;
  const uint4* pu = (const uint4*)(u + (size_t)row * 8192);
  float f[32];
#pragma unroll
  for (int k = 0; k < 4; ++k) {
    uint4 w = pu[tid + 256 * k];
    unsigned int ws4[4] = {w.x, w.y, w.z, w.w};
#pragma unroll
    for (int j = 0; j < 4; ++j) {
      f[k * 8 + j * 2 + 0] = bf2f((unsigned short)(ws4[j] & 0xFFFFu));
      f[k * 8 + j * 2 + 1] = bf2f((unsigned short)(ws4[j] >> 16));
    }
  }
  float m = 0.0f;
#pragma unroll
  for (int k = 0; k < 32; ++k) m = fmaxf(m, fabsf(f[k]));
  m = fmaxf(block_max256(m), EPSQ);
  const float s = 127.0f / m;
  if (tid == 0) rsx[row] = m / 127.0f;
  int* qp = (int*)(q + (size_t)row * 8192);
#pragma unroll
  for (int k = 0; k < 4; ++k) {
    qp[(tid + 256 * k) * 2 + 0] = packa4(f[k * 8 + 0], f[k * 8 + 1], f[k * 8 + 2], f[k * 8 + 3], s);
    qp[(tid + 256 * k) * 2 + 1] = packa4(f[k * 8 + 4], f[k * 8 + 5], f[k * 8 + 6], f[k * 8 + 7], s);
  }
}

// ---------- i8 GEMM, 128² tile, 4 waves (out-GEMM split-K site) ----------
// EPI: 4 = raw int32 partial (cached stores)
template<int EPI>
__global__ __launch_bounds__(256) void gemm_bt(
    const unsigned char* __restrict__ A, const unsigned char* __restrict__ Bw,
    const float* rsx, const float* wmean, const float* bias,
    float* outF, unsigned short* outB, int* outI,
    int M, int N, int K, int Ksz) {
  __shared__ unsigned char As[2][128 * 128];
  __shared__ unsigned char Bs[2][128 * 128];
  const int tid = threadIdx.x;

  const int gx = gridDim.x, gy = gridDim.y;
  const int orig = blockIdx.y * gx + blockIdx.x;
  const int xcd = orig & 7;
  const int local = orig >> 3;
  const int cn = (gx >= 32) ? 8 : 4;
  const int npx = gx / cn;
  const int n = (xcd % cn) * npx + (local % npx);
  const int m = (xcd / cn) * (gy / (8 / cn)) + (local / npx);
  const int brow = m << 7;
  const int bcol = n << 7;

  const int lane = tid & 63;
  const int wv = tid >> 6;
  const int wr = (wv >> 1) << 6;
  const int wc = (wv & 1) << 6;
  const int lr = lane & 15;
  const int lg = lane >> 4;

  i32x4 acc[4][4] = {};

  const int scol = (((tid & 7) ^ ((tid >> 3) & 7)) << 4);
  const size_t koff = (size_t)blockIdx.z * Ksz;
  const unsigned char* gA0 = A + (size_t)(brow + (tid >> 3)) * K + koff + scol;
  const unsigned char* gB0 = Bw + (size_t)(bcol + (tid >> 3)) * K + koff + scol;
  const int ldst = (tid & ~63) * 16;

  auto stage = [&](int b, int kt) {
#pragma unroll
    for (int c = 0; c < 4; ++c) {
      __builtin_amdgcn_global_load_lds(
          (const __attribute__((address_space(1))) void*)(gA0 + (size_t)kt * 128 + (size_t)c * 32 * K),
          (__attribute__((address_space(3))) void*)(&As[b][c * 4096 + ldst]),
          16, 0, 0);
      __builtin_amdgcn_global_load_lds(
          (const __attribute__((address_space(1))) void*)(gB0 + (size_t)kt * 128 + (size_t)c * 32 * K),
          (__attribute__((address_space(3))) void*)(&Bs[b][c * 4096 + ldst]),
          16, 0, 0);
    }
  };

  const int nkt = Ksz >> 7;
  stage(0, 0);
  stage(1, 1);

  for (int kt = 0; kt < nkt; ++kt) {
    const int cur = kt & 1;
    if (kt + 1 < nkt) {
      asm volatile("s_waitcnt vmcnt(8)" ::: "memory");
    } else {
      asm volatile("s_waitcnt vmcnt(0)" ::: "memory");
    }
    __builtin_amdgcn_s_barrier();
    __builtin_amdgcn_sched_barrier(0);
    __builtin_amdgcn_s_setprio(1);
#pragma unroll
    for (int kk = 0; kk < 2; ++kk) {
      i32x4 af[4], bfr[4];
#pragma unroll
      for (int i = 0; i < 4; ++i) {
        const int ra = wr + i * 16 + lr;
        const int rb = wc + i * 16 + lr;
        const int ch = (((kk << 2) | lg) ^ (lr & 7)) << 4;
        af[i]  = *(const i32x4*)(&As[cur][ra * 128 + ch]);
        bfr[i] = *(const i32x4*)(&Bs[cur][rb * 128 + ch]);
      }
#pragma unroll
      for (int i = 0; i < 4; ++i)
#pragma unroll
        for (int j = 0; j < 4; ++j)
          acc[i][j] = __builtin_amdgcn_mfma_i32_16x16x64_i8(af[i], bfr[j], acc[i][j], 0, 0, 0);
    }
    __builtin_amdgcn_s_setprio(0);
    __builtin_amdgcn_sched_barrier(0);
    __builtin_amdgcn_s_barrier();
    __builtin_amdgcn_sched_barrier(0);
    if (kt + 2 < nkt) stage(cur, kt + 2);
  }

  int* pI = outI + (size_t)blockIdx.z * M * N;
#pragma unroll
  for (int i = 0; i < 4; ++i) {
#pragma unroll
    for (int r = 0; r < 4; ++r) {
      const int row = brow + wr + i * 16 + lg * 4 + r;
#pragma unroll
      for (int j = 0; j < 4; ++j) {
        const int col = bcol + wc + j * 16 + lr;
        pI[(size_t)row * N + col] = acc[i][j][r];
      }
    }
  }
  (void)rsx; (void)wmean; (void)bias; (void)outF; (void)outB;
}

// ---------- i8 GEMM, 256² tile, 8 waves, 512 threads ----------
// EPI 1: gelu(scale+bias)->bf16 (fc1).  EPI 4: raw int32 partial, CACHED stores
// (round-17 post-mortem: NT stores on read-soon pacc forced HBM round-trips).
template<int EPI>
__global__ __launch_bounds__(512, 2) void gemm_256(
    const unsigned char* __restrict__ A,   // [M,K] int8
    const unsigned char* __restrict__ Bw,  // [N,K] int8 ternary
    const float* rsx, const float* wmean, const float* bias,
    unsigned short* outB, int* outI, int M, int N, int K, int Ksz) {
  __shared__ unsigned char As[2][256 * 128];
  __shared__ unsigned char Bs[2][256 * 128];
  const int tid = threadIdx.x;

  const int gx = gridDim.x, gy = gridDim.y;
  const int orig = blockIdx.y * gx + blockIdx.x;
  const int xcd = orig & 7;
  const int local = orig >> 3;
  const int cn = (gx >= 32) ? 8 : 4;
  const int npx = gx / cn;
  const int n = (xcd % cn) * npx + (local % npx);
  const int m = (xcd / cn) * (gy / (8 / cn)) + (local / npx);
  const int brow = m << 8;
  const int bcol = n << 8;

  const int lane = tid & 63;
  const int wv = tid >> 6;          // 0..7
  const int wr = (wv >> 2) << 7;    // 0 / 128
  const int wc = (wv & 3) << 6;     // 0 / 64 / 128 / 192
  const int lr = lane & 15;
  const int lg = lane >> 4;

  i32x4 acc[8][4] = {};

  const int scol = (((tid & 7) ^ ((tid >> 3) & 7)) << 4);
  const size_t koff = (size_t)blockIdx.z * Ksz;
  const unsigned char* gA0 = A + (size_t)(brow + (tid >> 3)) * K + koff + scol;
  const unsigned char* gB0 = Bw + (size_t)(bcol + (tid >> 3)) * K + koff + scol;
  const int ldst = (tid & ~63) * 16;

  auto stage = [&](int b, int kt) {
#pragma unroll
    for (int c = 0; c < 4; ++c) {
      __builtin_amdgcn_global_load_lds(
          (const __attribute__((address_space(1))) void*)(gA0 + (size_t)kt * 128 + (size_t)c * 64 * K),
          (__attribute__((address_space(3))) void*)(&As[b][c * 8192 + ldst]),
          16, 0, 0);
      __builtin_amdgcn_global_load_lds(
          (const __attribute__((address_space(1))) void*)(gB0 + (size_t)kt * 128 + (size_t)c * 64 * K),
          (__attribute__((address_space(3))) void*)(&Bs[b][c * 8192 + ldst]),
          16, 0, 0);
    }
  };

  const int nkt = Ksz >> 7;
  stage(0, 0);
  stage(1, 1);

  for (int kt = 0; kt < nkt; ++kt) {
    const int cur = kt & 1;
    if (kt + 1 < nkt) {
      asm volatile("s_waitcnt vmcnt(8)" ::: "memory");
    } else {
      asm volatile("s_waitcnt vmcnt(0)" ::: "memory");
    }
    __builtin_amdgcn_s_barrier();
    __builtin_amdgcn_sched_barrier(0);
    __builtin_amdgcn_s_setprio(1);
#pragma unroll
    for (int kk = 0; kk < 2; ++kk) {
      const int ch = (((kk << 2) | lg) ^ (lr & 7)) << 4;
      i32x4 af[8], bfr[4];
#pragma unroll
      for (int i = 0; i < 8; ++i)
        af[i] = *(const i32x4*)(&As[cur][(wr + i * 16 + lr) * 128 + ch]);
#pragma unroll
      for (int j = 0; j < 4; ++j)
        bfr[j] = *(const i32x4*)(&Bs[cur][(wc + j * 16 + lr) * 128 + ch]);
#pragma unroll
      for (int i = 0; i < 8; ++i)
#pragma unroll
        for (int j = 0; j < 4; ++j)
          acc[i][j] = __builtin_amdgcn_mfma_i32_16x16x64_i8(af[i], bfr[j], acc[i][j], 0, 0, 0);
    }
    __builtin_amdgcn_s_setprio(0);
    __builtin_amdgcn_sched_barrier(0);
    __builtin_amdgcn_s_barrier();
    __builtin_amdgcn_sched_barrier(0);
    if (kt + 2 < nkt) stage(cur, kt + 2);
  }

  if constexpr (EPI == 1) {
    const float mscale = wmean[0];
#pragma unroll
    for (int i = 0; i < 8; ++i) {
#pragma unroll
      for (int r = 0; r < 4; ++r) {
        const int row = brow + wr + i * 16 + lg * 4 + r;
        const float sc = rsx[row] * mscale;
#pragma unroll
        for (int j = 0; j < 4; ++j) {
          const int col = bcol + wc + j * 16 + lr;
          float v = (float)acc[i][j][r] * sc + bias[col];
          float g = 0.5f * v * (1.0f + erff(v * 0.70710678118654752f));
          outB[(size_t)row * N + col] = f2bf(g);
        }
      }
    }
  } else {
    int* pI = outI + (size_t)blockIdx.z * M * N;
#pragma unroll
    for (int i = 0; i < 8; ++i) {
#pragma unroll
      for (int r = 0; r < 4; ++r) {
        const int row = brow + wr + i * 16 + lg * 4 + r;
#pragma unroll
        for (int j = 0; j < 4; ++j) {
          const int col = bcol + wc + j * 16 + lr;
          pI[(size_t)row * N + col] = acc[i][j][r];
        }
      }
    }
  }
}

// ---------- fused split-K reduce + epilogue + act-quant (one block per row, N=2048) ----------
template<int EPI, bool WRITE_H>
__global__ __launch_bounds__(256) void reduce_qa(
    const int* __restrict__ part, int S, size_t MN,
    const float* __restrict__ wmean, const float* __restrict__ bias,
    float* __restrict__ hbuf, float* __restrict__ rsx,
    unsigned char* __restrict__ qa) {
  const int row = blockIdx.x, tid = threadIdx.x;
  const float sc = rsx[row] * wmean[0];
  const size_t rbase = (size_t)row * 2048;
  int4 v0 = *(const int4*)(part + rbase + (size_t)tid * 4);
  int4 v1 = *(const int4*)(part + rbase + (size_t)(tid + 256) * 4);
  for (int s = 1; s < S; ++s) {
    const int* ps = part + (size_t)s * MN + rbase;
    int4 a0 = *(const int4*)(ps + (size_t)tid * 4);
    int4 a1 = *(const int4*)(ps + (size_t)(tid + 256) * 4);
    v0.x += a0.x; v0.y += a0.y; v0.z += a0.z; v0.w += a0.w;
    v1.x += a1.x; v1.y += a1.y; v1.z += a1.z; v1.w += a1.w;
  }
  const float4 b0 = *(const float4*)(bias + tid * 4);
  const float4 b1 = *(const float4*)(bias + (tid + 256) * 4);
  float4 r0, r1;
  r0.x = (float)v0.x * sc + b0.x; r0.y = (float)v0.y * sc + b0.y;
  r0.z = (float)v0.z * sc + b0.z; r0.w = (float)v0.w * sc + b0.w;
  r1.x = (float)v1.x * sc + b1.x; r1.y = (float)v1.y * sc + b1.y;
  r1.z = (float)v1.z * sc + b1.z; r1.w = (float)v1.w * sc + b1.w;
  if constexpr (EPI == 2) {
    const float4 h0 = *(const float4*)(hbuf + rbase + (size_t)tid * 4);
    const float4 h1 = *(const float4*)(hbuf + rbase + (size_t)(tid + 256) * 4);
    r0.x += h0.x; r0.y += h0.y; r0.z += h0.z; r0.w += h0.w;
    r1.x += h1.x; r1.y += h1.y; r1.z += h1.z; r1.w += h1.w;
  }
  float m = fmaxf(fmaxf(fmaxf(fabsf(r0.x), fabsf(r0.y)), fmaxf(fabsf(r0.z), fabsf(r0.w))),
                  fmaxf(fmaxf(fabsf(r1.x), fabsf(r1.y)), fmaxf(fabsf(r1.z), fabsf(r1.w))));
  m = fmaxf(block_max256(m), EPSQ);              // barrier: sc reads done before rsx write
  const float s127 = 127.0f / m;
  if (tid == 0) rsx[row] = m / 127.0f;
  if constexpr (WRITE_H) {
    *(float4*)(hbuf + rbase + (size_t)tid * 4) = r0;
    *(float4*)(hbuf + rbase + (size_t)(tid + 256) * 4) = r1;
  }
  int* qp = (int*)(qa + rbase);
  qp[tid]       = packa4(r0.x, r0.y, r0.z, r0.w, s127);
  qp[tid + 256] = packa4(r1.x, r1.y, r1.z, r1.w, s127);
}

// ---------- final reduce: out = y + focus[m]*(v*sc + bias) ----------
__global__ __launch_bounds__(256) void reduce_final(
    const int* __restrict__ part, int S, int N, size_t MN,
    const float* rsx, const float* wmean, const float* bias,
    const float* aux, const float* focus, float* outF) {
  const size_t i4 = ((size_t)blockIdx.x * 256 + threadIdx.x) * 4;
  if (i4 >= MN) return;
  const int row = (int)(i4 / (unsigned)N);
  const int col = (int)(i4 % (unsigned)N);
  int4 v = *(const int4*)(part + i4);
  for (int s = 1; s < S; ++s) {
    int4 p = *(const int4*)(part + (size_t)s * MN + i4);
    v.x += p.x; v.y += p.y; v.z += p.z; v.w += p.w;
  }
  const float sc = rsx[row] * wmean[0];
  const float4 b = *(const float4*)(bias + col);
  const float4 a = *(const float4*)(aux + i4);
  const float fm = focus[row];
  float4 r;
  r.x = a.x + fm * ((float)v.x * sc + b.x);
  r.y = a.y + fm * ((float)v.y * sc + b.y);
  r.z = a.z + fm * ((float)v.z * sc + b.z);
  r.w = a.w + fm * ((float)v.w * sc + b.w);
  *(float4*)(outF + i4) = r;
}

// ---------------------------------------------------------------------------
extern "C" void kernel_launch(void* const* d_in, const int* in_sizes, int n_in,
                              void* d_out, int out_size, void* d_ws, size_t ws_size,
                              hipStream_t stream) {
  const float* x     = (const float*)d_in[0];
  const float* y     = (const float*)d_in[1];
  const float* z     = (const float*)d_in[2];
  const float* fmsk  = (const float*)d_in[3];
  const float* w_in  = (const float*)d_in[4];
  const float* b_in  = (const float*)d_in[5];
  const float* fc1_w = (const float*)d_in[6];
  const float* fc1_b = (const float*)d_in[7];
  const float* fc2_w = (const float*)d_in[8];
  const float* fc2_b = (const float*)d_in[9];
  const float* w_out = (const float*)d_in[10];
  const float* b_out = (const float*)d_in[11];
  float* out = (float*)d_out;

  const int M = 2048;          // B*S tokens
  const int D = 2048, H = 8192, K3 = 6144;
  const size_t MN = (size_t)M * D;

  // ---- ws layout ----
  char* ws = (char*)d_ws;
  size_t off = 0;
  auto alloc = [&](size_t bytes) { size_t r = off; off = (off + bytes + 255) & ~(size_t)255; return r; };
  unsigned char* wq_in   = (unsigned char*)(ws + alloc((size_t)D * K3));
  unsigned char* wq_fc10 = (unsigned char*)(ws + alloc((size_t)H * D));
  unsigned char* wq_fc11 = (unsigned char*)(ws + alloc((size_t)H * D));
  unsigned char* wq_fc20 = (unsigned char*)(ws + alloc((size_t)D * H));
  unsigned char* wq_fc21 = (unsigned char*)(ws + alloc((size_t)D * H));
  unsigned char* wq_out  = (unsigned char*)(ws + alloc((size_t)D * D));
  unsigned char* qact    = (unsigned char*)(ws + alloc((size_t)M * H));       // shared act-i8 buf
  unsigned short* ub     = (unsigned short*)(ws + alloc((size_t)M * H * 2));  // gelu out bf16
  float* hbuf            = (float*)(ws + alloc(MN * 4));
  float* rsx             = (float*)(ws + alloc((size_t)M * 4));
  float* wmean           = (float*)(ws + alloc(64));
  double* part           = (double*)(ws + alloc(16384 * 8));
  int* pacc              = (int*)(ws + alloc(MN * 4 * 4));                    // split-K partials (S<=4)
  (void)in_sizes; (void)n_in; (void)out_size; (void)ws_size;

  WTbl tbl;
  tbl.p[0] = w_in;                  tbl.q[0] = wq_in;
  tbl.p[1] = fc1_w;                 tbl.q[1] = wq_fc10;
  tbl.p[2] = fc1_w + (size_t)H * D; tbl.q[2] = wq_fc11;
  tbl.p[3] = fc2_w;                 tbl.q[3] = wq_fc20;
  tbl.p[4] = fc2_w + (size_t)D * H; tbl.q[4] = wq_fc21;
  tbl.p[5] = w_out;                 tbl.q[5] = wq_out;
  tbl.cum[0] = 0;
  tbl.cum[1] = 1536;
  tbl.cum[2] = 1536 + 2048;
  tbl.cum[3] = 1536 + 2 * 2048;
  tbl.cum[4] = 1536 + 3 * 2048;
  tbl.cum[5] = 1536 + 4 * 2048;
  tbl.cum[6] = 1536 + 4 * 2048 + 512;   // 10240 total chunks

  dim3 blk(256);
  const int NCH = 10240;
  wmean_partial<<<dim3(NCH), blk, 0, stream>>>(tbl, part);
  wmean_final<<<dim3(1), blk, 0, stream>>>(part, tbl, wmean);
  wquant<<<dim3(NCH), blk, 0, stream>>>(tbl, wmean);

  // h0 = bitlinear(cat(x,y,z), w_in, b_in); quantize rows for fc1 in the reduce
  aq_cat<<<dim3(M), blk, 0, stream>>>(x, y, z, qact, rsx);
  gemm_256<4><<<dim3(D / 256, M / 256, 4), dim3(512), 0, stream>>>(qact, wq_in, rsx, wmean + 0, b_in,
                                                                   nullptr, pacc, M, D, K3, K3 / 4);
  reduce_qa<0, true><<<dim3(M), blk, 0, stream>>>(pacc, 4, MN, wmean + 0, b_in,
                                                  hbuf, rsx, qact);

  unsigned char* wq_fc1[2] = {wq_fc10, wq_fc11};
  unsigned char* wq_fc2[2] = {wq_fc20, wq_fc21};
  for (int l = 0; l < 2; ++l) {
    gemm_256<1><<<dim3(H / 256, M / 256), dim3(512), 0, stream>>>(qact, wq_fc1[l], rsx, wmean + 1 + l,
                                                                  fc1_b + (size_t)l * H, ub, nullptr,
                                                                  M, H, D, D);
    aq_bf16<<<dim3(M), blk, 0, stream>>>(ub, qact, rsx);
    gemm_256<4><<<dim3(D / 256, M / 256, 4), dim3(512), 0, stream>>>(qact, wq_fc2[l], rsx, wmean + 3 + l,
                                                                     fc2_b + (size_t)l * D, nullptr, pacc,
                                                                     M, D, H, H / 4);
    if (l == 0) {
      reduce_qa<2, true><<<dim3(M), blk, 0, stream>>>(pacc, 4, MN, wmean + 3 + l,
                                                      fc2_b + (size_t)l * D, hbuf, rsx, qact);
    } else {
      reduce_qa<2, false><<<dim3(M), blk, 0, stream>>>(pacc, 4, MN, wmean + 3 + l,
                                                       fc2_b + (size_t)l * D, hbuf, rsx, qact);
    }
  }

  gemm_bt<4><<<dim3(D / 128, M / 128, 2), blk, 0, stream>>>(qact, wq_out, rsx, wmean + 5, b_out,
                                                            nullptr, nullptr, pacc, M, D, D, D / 2);
  reduce_final<<<dim3((int)((MN / 4 + 255) / 256)), blk, 0, stream>>>(pacc, 2, D, MN, rsx, wmean + 5, b_out,
                                                                      y, fmsk, out);
}

// Round 20
// 437.065 us; speedup vs baseline: 1.0681x; 1.0681x over previous
//
#include <hip/hip_runtime.h>

#define EPSQ 1e-5f

typedef int i32x4 __attribute__((ext_vector_type(4)));
typedef float f32x4n __attribute__((ext_vector_type(4)));   // native vec for NT loads

// ---------- helpers ----------
__device__ __forceinline__ unsigned short f2bf(float f) {
  unsigned int b = __builtin_bit_cast(unsigned int, f);
  b += 0x7FFFu + ((b >> 16) & 1u);            // RNE
  return (unsigned short)(b >> 16);
}
__device__ __forceinline__ float bf2f(unsigned short u) {
  unsigned int b = ((unsigned int)u) << 16;
  return __builtin_bit_cast(float, b);
}
// weights: ternary clip to [-1,1]
__device__ __forceinline__ int packw4(float a, float b, float c, float d, float inv) {
  int qa = (int)fminf(fmaxf(rintf(a * inv), -1.0f), 1.0f);
  int qb = (int)fminf(fmaxf(rintf(b * inv), -1.0f), 1.0f);
  int qc = (int)fminf(fmaxf(rintf(c * inv), -1.0f), 1.0f);
  int qd = (int)fminf(fmaxf(rintf(d * inv), -1.0f), 1.0f);
  return (qa & 255) | ((qb & 255) << 8) | ((qc & 255) << 16) | ((qd & 255) << 24);
}
// activations: clip to [-128,127]
__device__ __forceinline__ int packa4(float a, float b, float c, float d, float s) {
  int qa = (int)fminf(fmaxf(rintf(a * s), -128.0f), 127.0f);
  int qb = (int)fminf(fmaxf(rintf(b * s), -128.0f), 127.0f);
  int qc = (int)fminf(fmaxf(rintf(c * s), -128.0f), 127.0f);
  int qd = (int)fminf(fmaxf(rintf(d * s), -128.0f), 127.0f);
  return (qa & 255) | ((qb & 255) << 8) | ((qc & 255) << 16) | ((qd & 255) << 24);
}

// ---------- weight tensor table (flattened chunk mapping) ----------
struct WTbl {
  const float* p[6];
  unsigned char* q[6];
  unsigned int cum[7];
};

// ---------- stage 1: per-chunk |w| partial sums; NT reads (proven round 13) ----------
__global__ __launch_bounds__(256) void wmean_partial(WTbl tbl, double* __restrict__ part) {
  const int b = blockIdx.x;
  int t = 0;
#pragma unroll
  for (int i = 1; i < 6; ++i) t += (b >= (int)tbl.cum[i]);
  const f32x4n* __restrict__ p = (const f32x4n*)tbl.p[t];
  const unsigned int base = (unsigned)(b - (int)tbl.cum[t]) * 2048u + threadIdx.x;
  f32x4n v[8];
#pragma unroll
  for (int u = 0; u < 8; ++u) v[u] = __builtin_nontemporal_load(p + base + (unsigned)u * 256u);
  double s = 0.0;
#pragma unroll
  for (int u = 0; u < 8; ++u)
    s += (double)(fabsf(v[u][0]) + fabsf(v[u][1])) + (double)(fabsf(v[u][2]) + fabsf(v[u][3]));
  for (int off = 32; off; off >>= 1) s += __shfl_xor(s, off);
  __shared__ double wsum[4];
  if ((threadIdx.x & 63) == 0) wsum[threadIdx.x >> 6] = s;
  __syncthreads();
  if (threadIdx.x == 0) part[b] = (wsum[0] + wsum[1]) + (wsum[2] + wsum[3]);
}

// ---------- stage 2: finalize means ----------
__global__ __launch_bounds__(256) void wmean_final(const double* __restrict__ part,
                                                   WTbl tbl, float* wmean) {
  for (int t = 0; t < 6; ++t) {
    const int lo = (int)tbl.cum[t], hi = (int)tbl.cum[t + 1];
    double s = 0.0;
    for (int i = lo + (int)threadIdx.x; i < hi; i += 256) s += part[i];
    for (int off = 32; off; off >>= 1) s += __shfl_xor(s, off);
    __shared__ double w4[4];
    if ((threadIdx.x & 63) == 0) w4[threadIdx.x >> 6] = s;
    __syncthreads();
    if (threadIdx.x == 0) {
      const double n = (double)(hi - lo) * 8192.0;
      float m = (float)(((w4[0] + w4[1]) + (w4[2] + w4[3])) / n);
      if (m < EPSQ) m = EPSQ;
      wmean[t] = m;
    }
    __syncthreads();
  }
}

// ---------- stage 3: ternary quantize -> int8; NT reads ----------
__global__ __launch_bounds__(256) void wquant(WTbl tbl, const float* wmean) {
  const int b = blockIdx.x;
  int t = 0;
#pragma unroll
  for (int i = 1; i < 6; ++i) t += (b >= (int)tbl.cum[i]);
  const float inv = 1.0f / wmean[t];
  const f32x4n* __restrict__ p = (const f32x4n*)tbl.p[t];
  int* __restrict__ q = (int*)tbl.q[t];
  const unsigned int base = (unsigned)(b - (int)tbl.cum[t]) * 2048u + threadIdx.x;
  f32x4n v[8];
#pragma unroll
  for (int u = 0; u < 8; ++u) v[u] = __builtin_nontemporal_load(p + base + (unsigned)u * 256u);
#pragma unroll
  for (int u = 0; u < 8; ++u)
    q[base + (unsigned)u * 256u] = packw4(v[u][0], v[u][1], v[u][2], v[u][3], inv);
}

// ---------- block max reduce helper ----------
__device__ __forceinline__ float block_max256(float m) {
  for (int off = 32; off; off >>= 1) m = fmaxf(m, __shfl_xor(m, off));
  __shared__ float wm[4];
  if ((threadIdx.x & 63) == 0) wm[threadIdx.x >> 6] = m;
  __syncthreads();
  return fmaxf(fmaxf(wm[0], wm[1]), fmaxf(wm[2], wm[3]));
}

// ---------- act quant: concat(x,y,z) row (6144) -> int8 + rsx ----------
__global__ __launch_bounds__(256) void aq_cat(const float* x, const float* y, const float* z,
                                              unsigned char* q, float* rsx) {
  const int row = blockIdx.x, tid = threadIdx.x;
  const float4* px = (const float4*)(x + (size_t)row * 2048);
  const float4* py = (const float4*)(y + (size_t)row * 2048);
  const float4* pz = (const float4*)(z + (size_t)row * 2048);
  float4 v[6];
  v[0] = px[tid]; v[1] = px[tid + 256];
  v[2] = py[tid]; v[3] = py[tid + 256];
  v[4] = pz[tid]; v[5] = pz[tid + 256];
  float m = 0.0f;
#pragma unroll
  for (int k = 0; k < 6; ++k)
    m = fmaxf(m, fmaxf(fmaxf(fabsf(v[k].x), fabsf(v[k].y)), fmaxf(fabsf(v[k].z), fabsf(v[k].w))));
  m = fmaxf(block_max256(m), EPSQ);
  const float s = 127.0f / m;
  if (tid == 0) rsx[row] = m / 127.0f;
  int* qr = (int*)(q + (size_t)row * 6144);
#pragma unroll
  for (int k = 0; k < 6; ++k) qr[k * 256 + tid] = packa4(v[k].x, v[k].y, v[k].z, v[k].w, s);
}

// ---------- act quant: bf16 row (8192) -> int8 ----------
__global__ __launch_bounds__(256) void aq_bf16(const unsigned short* u, unsigned char* q, float* rsx) {
  const int row = blockIdx.x, tid = threadIdx.x;
  const uint4* pu = (const uint4*)(u + (size_t)row * 8192);
  float f[32];
#pragma unroll
  for (int k = 0; k < 4; ++k) {
    uint4 w = pu[tid + 256 * k];
    unsigned int ws4[4] = {w.x, w.y, w.z, w.w};
#pragma unroll
    for (int j = 0; j < 4; ++j) {
      f[k * 8 + j * 2 + 0] = bf2f((unsigned short)(ws4[j] & 0xFFFFu));
      f[k * 8 + j * 2 + 1] = bf2f((unsigned short)(ws4[j] >> 16));
    }
  }
  float m = 0.0f;
#pragma unroll
  for (int k = 0; k < 32; ++k) m = fmaxf(m, fabsf(f[k]));
  m = fmaxf(block_max256(m), EPSQ);
  const float s = 127.0f / m;
  if (tid == 0) rsx[row] = m / 127.0f;
  int* qp = (int*)(q + (size_t)row * 8192);
#pragma unroll
  for (int k = 0; k < 4; ++k) {
    qp[(tid + 256 * k) * 2 + 0] = packa4(f[k * 8 + 0], f[k * 8 + 1], f[k * 8 + 2], f[k * 8 + 3], s);
    qp[(tid + 256 * k) * 2 + 1] = packa4(f[k * 8 + 4], f[k * 8 + 5], f[k * 8 + 6], f[k * 8 + 7], s);
  }
}

// ---------- i8 GEMM, 128² tile, 4 waves (split-K sites: gemm0, fc2, out) ----------
// EPI: 1 = gelu->bf16   4 = raw int32 partial
template<int EPI>
__global__ __launch_bounds__(256) void gemm_bt(
    const unsigned char* __restrict__ A, const unsigned char* __restrict__ Bw,
    const float* rsx, const float* wmean, const float* bias,
    float* outF, unsigned short* outB, int* outI,
    int M, int N, int K, int Ksz) {
  __shared__ unsigned char As[2][128 * 128];
  __shared__ unsigned char Bs[2][128 * 128];
  const int tid = threadIdx.x;

  const int gx = gridDim.x, gy = gridDim.y;
  const int orig = blockIdx.y * gx + blockIdx.x;
  const int xcd = orig & 7;
  const int local = orig >> 3;
  const int cn = (gx >= 32) ? 8 : 4;
  const int npx = gx / cn;
  const int n = (xcd % cn) * npx + (local % npx);
  const int m = (xcd / cn) * (gy / (8 / cn)) + (local / npx);
  const int brow = m << 7;
  const int bcol = n << 7;

  const int lane = tid & 63;
  const int wv = tid >> 6;
  const int wr = (wv >> 1) << 6;
  const int wc = (wv & 1) << 6;
  const int lr = lane & 15;
  const int lg = lane >> 4;

  i32x4 acc[4][4] = {};

  const int scol = (((tid & 7) ^ ((tid >> 3) & 7)) << 4);
  const size_t koff = (size_t)blockIdx.z * Ksz;
  const unsigned char* gA0 = A + (size_t)(brow + (tid >> 3)) * K + koff + scol;
  const unsigned char* gB0 = Bw + (size_t)(bcol + (tid >> 3)) * K + koff + scol;
  const int ldst = (tid & ~63) * 16;

  auto stage = [&](int b, int kt) {
#pragma unroll
    for (int c = 0; c < 4; ++c) {
      __builtin_amdgcn_global_load_lds(
          (const __attribute__((address_space(1))) void*)(gA0 + (size_t)kt * 128 + (size_t)c * 32 * K),
          (__attribute__((address_space(3))) void*)(&As[b][c * 4096 + ldst]),
          16, 0, 0);
      __builtin_amdgcn_global_load_lds(
          (const __attribute__((address_space(1))) void*)(gB0 + (size_t)kt * 128 + (size_t)c * 32 * K),
          (__attribute__((address_space(3))) void*)(&Bs[b][c * 4096 + ldst]),
          16, 0, 0);
    }
  };

  const int nkt = Ksz >> 7;
  stage(0, 0);
  stage(1, 1);

  for (int kt = 0; kt < nkt; ++kt) {
    const int cur = kt & 1;
    if (kt + 1 < nkt) {
      asm volatile("s_waitcnt vmcnt(8)" ::: "memory");
    } else {
      asm volatile("s_waitcnt vmcnt(0)" ::: "memory");
    }
    __builtin_amdgcn_s_barrier();
    __builtin_amdgcn_sched_barrier(0);
    __builtin_amdgcn_s_setprio(1);
#pragma unroll
    for (int kk = 0; kk < 2; ++kk) {
      i32x4 af[4], bfr[4];
#pragma unroll
      for (int i = 0; i < 4; ++i) {
        const int ra = wr + i * 16 + lr;
        const int rb = wc + i * 16 + lr;
        const int ch = (((kk << 2) | lg) ^ (lr & 7)) << 4;
        af[i]  = *(const i32x4*)(&As[cur][ra * 128 + ch]);
        bfr[i] = *(const i32x4*)(&Bs[cur][rb * 128 + ch]);
      }
#pragma unroll
      for (int i = 0; i < 4; ++i)
#pragma unroll
        for (int j = 0; j < 4; ++j)
          acc[i][j] = __builtin_amdgcn_mfma_i32_16x16x64_i8(af[i], bfr[j], acc[i][j], 0, 0, 0);
    }
    __builtin_amdgcn_s_setprio(0);
    __builtin_amdgcn_sched_barrier(0);
    __builtin_amdgcn_s_barrier();
    __builtin_amdgcn_sched_barrier(0);
    if (kt + 2 < nkt) stage(cur, kt + 2);
  }

  const float mscale = (EPI == 4) ? 0.0f : wmean[0];
  int* pI = (EPI == 4) ? (outI + (size_t)blockIdx.z * M * N) : nullptr;
#pragma unroll
  for (int i = 0; i < 4; ++i) {
#pragma unroll
    for (int r = 0; r < 4; ++r) {
      const int row = brow + wr + i * 16 + lg * 4 + r;
      const float sc = (EPI == 4) ? 1.0f : rsx[row] * mscale;
#pragma unroll
      for (int j = 0; j < 4; ++j) {
        const int col = bcol + wc + j * 16 + lr;
        const size_t o = (size_t)row * N + col;
        if constexpr (EPI == 4) {
          pI[o] = acc[i][j][r];
        } else {
          float v = (float)acc[i][j][r] * sc + bias[col];
          float g = 0.5f * v * (1.0f + erff(v * 0.70710678118654752f));
          outB[o] = f2bf(g);
        }
      }
    }
  }
}

// ---------- i8 GEMM, 256² tile, 8 waves, 512 threads (fc1: full-K, direct output) ----------
// 256² only pays for full-K direct-output GEMMs (round-16 win); split-K sites
// regressed at 256²/S=4 (rounds 17/19) -> those stay 128²/S=2.
__global__ __launch_bounds__(512, 2) void gemm_fc1(
    const unsigned char* __restrict__ A,   // [M,K] int8
    const unsigned char* __restrict__ Bw,  // [N,K] int8 ternary
    const float* rsx, const float* wmean, const float* bias,
    unsigned short* outB, int M, int N, int K) {
  __shared__ unsigned char As[2][256 * 128];
  __shared__ unsigned char Bs[2][256 * 128];
  const int tid = threadIdx.x;

  const int gx = gridDim.x, gy = gridDim.y;
  const int orig = blockIdx.y * gx + blockIdx.x;
  const int xcd = orig & 7;
  const int local = orig >> 3;
  const int cn = (gx >= 32) ? 8 : 4;
  const int npx = gx / cn;
  const int n = (xcd % cn) * npx + (local % npx);
  const int m = (xcd / cn) * (gy / (8 / cn)) + (local / npx);
  const int brow = m << 8;
  const int bcol = n << 8;

  const int lane = tid & 63;
  const int wv = tid >> 6;          // 0..7
  const int wr = (wv >> 2) << 7;    // 0 / 128
  const int wc = (wv & 3) << 6;     // 0 / 64 / 128 / 192
  const int lr = lane & 15;
  const int lg = lane >> 4;

  i32x4 acc[8][4] = {};

  const int scol = (((tid & 7) ^ ((tid >> 3) & 7)) << 4);
  const unsigned char* gA0 = A + (size_t)(brow + (tid >> 3)) * K + scol;
  const unsigned char* gB0 = Bw + (size_t)(bcol + (tid >> 3)) * K + scol;
  const int ldst = (tid & ~63) * 16;

  auto stage = [&](int b, int kt) {
#pragma unroll
    for (int c = 0; c < 4; ++c) {
      __builtin_amdgcn_global_load_lds(
          (const __attribute__((address_space(1))) void*)(gA0 + (size_t)kt * 128 + (size_t)c * 64 * K),
          (__attribute__((address_space(3))) void*)(&As[b][c * 8192 + ldst]),
          16, 0, 0);
      __builtin_amdgcn_global_load_lds(
          (const __attribute__((address_space(1))) void*)(gB0 + (size_t)kt * 128 + (size_t)c * 64 * K),
          (__attribute__((address_space(3))) void*)(&Bs[b][c * 8192 + ldst]),
          16, 0, 0);
    }
  };

  const int nkt = K >> 7;            // 128 bytes of K per tile
  stage(0, 0);
  stage(1, 1);

  for (int kt = 0; kt < nkt; ++kt) {
    const int cur = kt & 1;
    if (kt + 1 < nkt) {
      asm volatile("s_waitcnt vmcnt(8)" ::: "memory");
    } else {
      asm volatile("s_waitcnt vmcnt(0)" ::: "memory");
    }
    __builtin_amdgcn_s_barrier();
    __builtin_amdgcn_sched_barrier(0);
    __builtin_amdgcn_s_setprio(1);
#pragma unroll
    for (int kk = 0; kk < 2; ++kk) {
      const int ch = (((kk << 2) | lg) ^ (lr & 7)) << 4;
      i32x4 af[8], bfr[4];
#pragma unroll
      for (int i = 0; i < 8; ++i)
        af[i] = *(const i32x4*)(&As[cur][(wr + i * 16 + lr) * 128 + ch]);
#pragma unroll
      for (int j = 0; j < 4; ++j)
        bfr[j] = *(const i32x4*)(&Bs[cur][(wc + j * 16 + lr) * 128 + ch]);
#pragma unroll
      for (int i = 0; i < 8; ++i)
#pragma unroll
        for (int j = 0; j < 4; ++j)
          acc[i][j] = __builtin_amdgcn_mfma_i32_16x16x64_i8(af[i], bfr[j], acc[i][j], 0, 0, 0);
    }
    __builtin_amdgcn_s_setprio(0);
    __builtin_amdgcn_sched_barrier(0);
    __builtin_amdgcn_s_barrier();
    __builtin_amdgcn_sched_barrier(0);
    if (kt + 2 < nkt) stage(cur, kt + 2);
  }

  const float mscale = wmean[0];
#pragma unroll
  for (int i = 0; i < 8; ++i) {
#pragma unroll
    for (int r = 0; r < 4; ++r) {
      const int row = brow + wr + i * 16 + lg * 4 + r;
      const float sc = rsx[row] * mscale;
#pragma unroll
      for (int j = 0; j < 4; ++j) {
        const int col = bcol + wc + j * 16 + lr;
        float v = (float)acc[i][j][r] * sc + bias[col];
        float g = 0.5f * v * (1.0f + erff(v * 0.70710678118654752f));
        outB[(size_t)row * N + col] = f2bf(g);
      }
    }
  }
}

// ---------- fused split-K reduce + epilogue + act-quant (one block per row, N=2048) ----------
template<int EPI, bool WRITE_H>
__global__ __launch_bounds__(256) void reduce_qa(
    const int* __restrict__ part, int S, size_t MN,
    const float* __restrict__ wmean, const float* __restrict__ bias,
    float* __restrict__ hbuf, float* __restrict__ rsx,
    unsigned char* __restrict__ qa) {
  const int row = blockIdx.x, tid = threadIdx.x;
  const float sc = rsx[row] * wmean[0];
  const size_t rbase = (size_t)row * 2048;
  int4 v0 = *(const int4*)(part + rbase + (size_t)tid * 4);
  int4 v1 = *(const int4*)(part + rbase + (size_t)(tid + 256) * 4);
  for (int s = 1; s < S; ++s) {
    const int* ps = part + (size_t)s * MN + rbase;
    int4 a0 = *(const int4*)(ps + (size_t)tid * 4);
    int4 a1 = *(const int4*)(ps + (size_t)(tid + 256) * 4);
    v0.x += a0.x; v0.y += a0.y; v0.z += a0.z; v0.w += a0.w;
    v1.x += a1.x; v1.y += a1.y; v1.z += a1.z; v1.w += a1.w;
  }
  const float4 b0 = *(const float4*)(bias + tid * 4);
  const float4 b1 = *(const float4*)(bias + (tid + 256) * 4);
  float4 r0, r1;
  r0.x = (float)v0.x * sc + b0.x; r0.y = (float)v0.y * sc + b0.y;
  r0.z = (float)v0.z * sc + b0.z; r0.w = (float)v0.w * sc + b0.w;
  r1.x = (float)v1.x * sc + b1.x; r1.y = (float)v1.y * sc + b1.y;
  r1.z = (float)v1.z * sc + b1.z; r1.w = (float)v1.w * sc + b1.w;
  if constexpr (EPI == 2) {
    const float4 h0 = *(const float4*)(hbuf + rbase + (size_t)tid * 4);
    const float4 h1 = *(const float4*)(hbuf + rbase + (size_t)(tid + 256) * 4);
    r0.x += h0.x; r0.y += h0.y; r0.z += h0.z; r0.w += h0.w;
    r1.x += h1.x; r1.y += h1.y; r1.z += h1.z; r1.w += h1.w;
  }
  float m = fmaxf(fmaxf(fmaxf(fabsf(r0.x), fabsf(r0.y)), fmaxf(fabsf(r0.z), fabsf(r0.w))),
                  fmaxf(fmaxf(fabsf(r1.x), fabsf(r1.y)), fmaxf(fabsf(r1.z), fabsf(r1.w))));
  m = fmaxf(block_max256(m), EPSQ);              // barrier: sc reads done before rsx write
  const float s127 = 127.0f / m;
  if (tid == 0) rsx[row] = m / 127.0f;
  if constexpr (WRITE_H) {
    *(float4*)(hbuf + rbase + (size_t)tid * 4) = r0;
    *(float4*)(hbuf + rbase + (size_t)(tid + 256) * 4) = r1;
  }
  int* qp = (int*)(qa + rbase);
  qp[tid]       = packa4(r0.x, r0.y, r0.z, r0.w, s127);
  qp[tid + 256] = packa4(r1.x, r1.y, r1.z, r1.w, s127);
}

// ---------- final reduce: out = y + focus[m]*(v*sc + bias) ----------
__global__ __launch_bounds__(256) void reduce_final(
    const int* __restrict__ part, int S, int N, size_t MN,
    const float* rsx, const float* wmean, const float* bias,
    const float* aux, const float* focus, float* outF) {
  const size_t i4 = ((size_t)blockIdx.x * 256 + threadIdx.x) * 4;
  if (i4 >= MN) return;
  const int row = (int)(i4 / (unsigned)N);
  const int col = (int)(i4 % (unsigned)N);
  int4 v = *(const int4*)(part + i4);
  for (int s = 1; s < S; ++s) {
    int4 p = *(const int4*)(part + (size_t)s * MN + i4);
    v.x += p.x; v.y += p.y; v.z += p.z; v.w += p.w;
  }
  const float sc = rsx[row] * wmean[0];
  const float4 b = *(const float4*)(bias + col);
  const float4 a = *(const float4*)(aux + i4);
  const float fm = focus[row];
  float4 r;
  r.x = a.x + fm * ((float)v.x * sc + b.x);
  r.y = a.y + fm * ((float)v.y * sc + b.y);
  r.z = a.z + fm * ((float)v.z * sc + b.z);
  r.w = a.w + fm * ((float)v.w * sc + b.w);
  *(float4*)(outF + i4) = r;
}

// ---------------------------------------------------------------------------
extern "C" void kernel_launch(void* const* d_in, const int* in_sizes, int n_in,
                              void* d_out, int out_size, void* d_ws, size_t ws_size,
                              hipStream_t stream) {
  const float* x     = (const float*)d_in[0];
  const float* y     = (const float*)d_in[1];
  const float* z     = (const float*)d_in[2];
  const float* fmsk  = (const float*)d_in[3];
  const float* w_in  = (const float*)d_in[4];
  const float* b_in  = (const float*)d_in[5];
  const float* fc1_w = (const float*)d_in[6];
  const float* fc1_b = (const float*)d_in[7];
  const float* fc2_w = (const float*)d_in[8];
  const float* fc2_b = (const float*)d_in[9];
  const float* w_out = (const float*)d_in[10];
  const float* b_out = (const float*)d_in[11];
  float* out = (float*)d_out;

  const int M = 2048;          // B*S tokens
  const int D = 2048, H = 8192, K3 = 6144;
  const size_t MN = (size_t)M * D;

  // ---- ws layout ----
  char* ws = (char*)d_ws;
  size_t off = 0;
  auto alloc = [&](size_t bytes) { size_t r = off; off = (off + bytes + 255) & ~(size_t)255; return r; };
  unsigned char* wq_in   = (unsigned char*)(ws + alloc((size_t)D * K3));
  unsigned char* wq_fc10 = (unsigned char*)(ws + alloc((size_t)H * D));
  unsigned char* wq_fc11 = (unsigned char*)(ws + alloc((size_t)H * D));
  unsigned char* wq_fc20 = (unsigned char*)(ws + alloc((size_t)D * H));
  unsigned char* wq_fc21 = (unsigned char*)(ws + alloc((size_t)D * H));
  unsigned char* wq_out  = (unsigned char*)(ws + alloc((size_t)D * D));
  unsigned char* qact    = (unsigned char*)(ws + alloc((size_t)M * H));       // shared act-i8 buf
  unsigned short* ub     = (unsigned short*)(ws + alloc((size_t)M * H * 2));  // gelu out bf16
  float* hbuf            = (float*)(ws + alloc(MN * 4));
  float* rsx             = (float*)(ws + alloc((size_t)M * 4));
  float* wmean           = (float*)(ws + alloc(64));
  double* part           = (double*)(ws + alloc(16384 * 8));
  int* pacc              = (int*)(ws + alloc(MN * 2 * 4));                    // split-K partials (S=2)
  (void)in_sizes; (void)n_in; (void)out_size; (void)ws_size;

  WTbl tbl;
  tbl.p[0] = w_in;                  tbl.q[0] = wq_in;
  tbl.p[1] = fc1_w;                 tbl.q[1] = wq_fc10;
  tbl.p[2] = fc1_w + (size_t)H * D; tbl.q[2] = wq_fc11;
  tbl.p[3] = fc2_w;                 tbl.q[3] = wq_fc20;
  tbl.p[4] = fc2_w + (size_t)D * H; tbl.q[4] = wq_fc21;
  tbl.p[5] = w_out;                 tbl.q[5] = wq_out;
  tbl.cum[0] = 0;
  tbl.cum[1] = 1536;
  tbl.cum[2] = 1536 + 2048;
  tbl.cum[3] = 1536 + 2 * 2048;
  tbl.cum[4] = 1536 + 3 * 2048;
  tbl.cum[5] = 1536 + 4 * 2048;
  tbl.cum[6] = 1536 + 4 * 2048 + 512;   // 10240 total chunks

  dim3 blk(256);
  const int NCH = 10240;
  wmean_partial<<<dim3(NCH), blk, 0, stream>>>(tbl, part);
  wmean_final<<<dim3(1), blk, 0, stream>>>(part, tbl, wmean);
  wquant<<<dim3(NCH), blk, 0, stream>>>(tbl, wmean);

  // h0 = bitlinear(cat(x,y,z), w_in, b_in); quantize rows for fc1 in the reduce
  aq_cat<<<dim3(M), blk, 0, stream>>>(x, y, z, qact, rsx);
  gemm_bt<4><<<dim3(D / 128, M / 128, 2), blk, 0, stream>>>(qact, wq_in, rsx, wmean + 0, b_in,
                                                            nullptr, nullptr, pacc, M, D, K3, K3 / 2);
  reduce_qa<0, true><<<dim3(M), blk, 0, stream>>>(pacc, 2, MN, wmean + 0, b_in,
                                                  hbuf, rsx, qact);

  unsigned char* wq_fc1[2] = {wq_fc10, wq_fc11};
  unsigned char* wq_fc2[2] = {wq_fc20, wq_fc21};
  for (int l = 0; l < 2; ++l) {
    gemm_fc1<<<dim3(H / 256, M / 256), dim3(512), 0, stream>>>(qact, wq_fc1[l], rsx, wmean + 1 + l,
                                                               fc1_b + (size_t)l * H, ub, M, H, D);
    aq_bf16<<<dim3(M), blk, 0, stream>>>(ub, qact, rsx);
    gemm_bt<4><<<dim3(D / 128, M / 128, 2), blk, 0, stream>>>(qact, wq_fc2[l], rsx, wmean + 3 + l,
                                                              fc2_b + (size_t)l * D,
                                                              nullptr, nullptr, pacc, M, D, H, H / 2);
    if (l == 0) {
      reduce_qa<2, true><<<dim3(M), blk, 0, stream>>>(pacc, 2, MN, wmean + 3 + l,
                                                      fc2_b + (size_t)l * D, hbuf, rsx, qact);
    } else {
      reduce_qa<2, false><<<dim3(M), blk, 0, stream>>>(pacc, 2, MN, wmean + 3 + l,
                                                       fc2_b + (size_t)l * D, hbuf, rsx, qact);
    }
  }

  gemm_bt<4><<<dim3(D / 128, M / 128, 2), blk, 0, stream>>>(qact, wq_out, rsx, wmean + 5, b_out,
                                                            nullptr, nullptr, pacc, M, D, D, D / 2);
  reduce_final<<<dim3((int)((MN / 4 + 255) / 256)), blk, 0, stream>>>(pacc, 2, D, MN, rsx, wmean + 5, b_out,
                                                                      y, fmsk, out);
}